// Round 2
// baseline (698.955 us; speedup 1.0000x reference)
//
#include <hip/hip_runtime.h>

#define B_      16
#define CIN_    512
#define COUT_   3
#define WDIM_   512
#define HW4_    4096             // 128*128/4 float4 per plane
#define FC_GAIN     0.044194173824159216f   // 1/sqrt(512)
#define WEIGHT_GAIN 0.044194173824159216f   // 1/sqrt(512*1)
#define CLAMP_  256.0f

#define NGRP_   16               // channel groups (512/32)
#define CPG_    32               // channels per group
#define NTILE_  4                // pixel tiles per plane
#define TSZ_    1024             // float4 per tile (16 KB contiguous per plane)
#define K_      4                // float4 chunks per thread (256 thr * 4 = TSZ_)
#define PART_OFF_ 131072         // float4 offset into d_ws for partials (2 MB)

// Kernel 1: one wave per (b, c). Unchanged from round 0 (measured ~8 us, L2-resident).
__global__ __launch_bounds__(64) void style_kernel(
    const float* __restrict__ w,
    const float* __restrict__ affine_W,
    const float* __restrict__ affine_b,
    const float* __restrict__ conv_w,
    float4* __restrict__ eff4) {
  const int bc   = blockIdx.x;        // 0 .. B*CIN-1
  const int b    = bc >> 9;
  const int c    = bc & 511;
  const int lane = threadIdx.x;

  const float* wb = w + b * WDIM_;
  const float* r1 = affine_W + (size_t)c * WDIM_;
  const float* r2 = affine_W + (size_t)(c + CIN_) * WDIM_;
  const float* r3 = affine_W + (size_t)(c + 2 * CIN_) * WDIM_;

  float p1 = 0.f, p2 = 0.f, p3 = 0.f;
#pragma unroll
  for (int j = 0; j < WDIM_ / 64; ++j) {
    const int k = j * 64 + lane;
    const float wk = wb[k];
    p1 = fmaf(wk, r1[k], p1);
    p2 = fmaf(wk, r2[k], p2);
    p3 = fmaf(wk, r3[k], p3);
  }
#pragma unroll
  for (int off = 32; off > 0; off >>= 1) {
    p1 += __shfl_down(p1, off);
    p2 += __shfl_down(p2, off);
    p3 += __shfl_down(p3, off);
  }
  if (lane == 0) {
    const float s1 = p1 * FC_GAIN + affine_b[c];
    const float s2 = p2 * FC_GAIN + affine_b[c + CIN_];
    const float s3 = p3 * FC_GAIN + affine_b[c + 2 * CIN_];
    const float style = (s1 * s2 + s3) * WEIGHT_GAIN;
    float4 e;
    e.x = conv_w[0 * CIN_ + c] * style;
    e.y = conv_w[1 * CIN_ + c] * style;
    e.z = conv_w[2 * CIN_ + c] * style;
    e.w = 0.f;
    eff4[bc] = e;
  }
}

#define FMA4(acc, xv, s)                                      \
  acc.x = fmaf(xv.x, (s), acc.x); acc.y = fmaf(xv.y, (s), acc.y); \
  acc.z = fmaf(xv.z, (s), acc.z); acc.w = fmaf(xv.w, (s), acc.w);

// Kernel 2a: channel-group partials.
// grid = 16 b * 4 tiles * 16 groups = 1024 blocks of 256 (4 blocks/CU).
// Block (b, tile, g): reads a 16 KB-wide contiguous pixel stripe (TSZ_=1024
// float4) of each of its 32 channel planes. Concurrent loads per wave span
// 4 pixel chunks (4 KB apart) x 2 unrolled channels -> in-flight addresses
// vary in pixel bits [14:12] as well as channel bits [>=16], breaking the
// pure-64KB-stride L2-set/bank resonance of rounds 0/1.
__global__ __launch_bounds__(256, 4) void conv_partial_kernel(
    const float* __restrict__ x,
    const float4* __restrict__ eff4,
    float4* __restrict__ part) {
  __shared__ float4 s_eff[CPG_];

  const int bx   = blockIdx.x;       // b*64 + tile*16 + g
  const int b    = bx >> 6;          // 0..15
  const int tile = (bx >> 4) & 3;    // 0..3
  const int g    = bx & 15;          // 0..15
  const int tid  = threadIdx.x;

  if (tid < CPG_) s_eff[tid] = eff4[b * CIN_ + g * CPG_ + tid];
  __syncthreads();

  const float4* xb = (const float4*)x
      + ((size_t)b * CIN_ + (size_t)g * CPG_) * HW4_
      + (size_t)tile * TSZ_ + tid;

  float4 a0[K_], a1[K_], a2[K_];
#pragma unroll
  for (int k = 0; k < K_; ++k) {
    a0[k] = make_float4(0.f, 0.f, 0.f, 0.f);
    a1[k] = make_float4(0.f, 0.f, 0.f, 0.f);
    a2[k] = make_float4(0.f, 0.f, 0.f, 0.f);
  }

#pragma unroll 2
  for (int c = 0; c < CPG_; ++c) {
    float4 xv[K_];
#pragma unroll
    for (int k = 0; k < K_; ++k) xv[k] = xb[(size_t)c * HW4_ + k * 256];
    const float4 e = s_eff[c];
#pragma unroll
    for (int k = 0; k < K_; ++k) {
      FMA4(a0[k], xv[k], e.x);
      FMA4(a1[k], xv[k], e.y);
      FMA4(a2[k], xv[k], e.z);
    }
  }

  // part[((b*16+g)*3+o)*4096 + tile*1024 + k*256 + tid] — coalesced 16 KB/o
  float4* pb = part + ((size_t)(b * NGRP_ + g) * COUT_) * HW4_
               + (size_t)tile * TSZ_ + tid;
#pragma unroll
  for (int k = 0; k < K_; ++k) {
    pb[k * 256]                = a0[k];
    pb[k * 256 + 1 * HW4_]     = a1[k];
    pb[k * 256 + 2 * HW4_]     = a2[k];
  }
}

// Kernel 2b: sum the 16 group-partials, add bias, clamp, store.
// grid = 16 b * 3 o * 4 tiles = 192 blocks of 256. Reads 48 MB, writes 3 MB.
__global__ __launch_bounds__(256) void reduce_kernel(
    const float4* __restrict__ part,
    const float* __restrict__ conv_b,
    float4* __restrict__ out4) {
  const int bx   = blockIdx.x;      // b*12 + o*4 + tile
  const int b    = bx / 12;
  const int r    = bx % 12;
  const int o    = r >> 2;
  const int tile = r & 3;
  const int tid  = threadIdx.x;

  float4 acc[K_];
#pragma unroll
  for (int k = 0; k < K_; ++k) acc[k] = make_float4(0.f, 0.f, 0.f, 0.f);

  for (int g = 0; g < NGRP_; ++g) {
    const float4* pp = part + ((size_t)(b * NGRP_ + g) * COUT_ + o) * HW4_
                       + (size_t)tile * TSZ_ + tid;
#pragma unroll
    for (int k = 0; k < K_; ++k) {
      const float4 v = pp[k * 256];
      acc[k].x += v.x; acc[k].y += v.y; acc[k].z += v.z; acc[k].w += v.w;
    }
  }

  const float bb = conv_b[o];
#define CLMP(v) fminf(fmaxf((v) + bb, -CLAMP_), CLAMP_)
  float4* op = out4 + ((size_t)b * COUT_ + o) * HW4_ + (size_t)tile * TSZ_ + tid;
#pragma unroll
  for (int k = 0; k < K_; ++k) {
    op[k * 256] = make_float4(CLMP(acc[k].x), CLMP(acc[k].y),
                              CLMP(acc[k].z), CLMP(acc[k].w));
  }
#undef CLMP
}

extern "C" void kernel_launch(void* const* d_in, const int* in_sizes, int n_in,
                              void* d_out, int out_size, void* d_ws, size_t ws_size,
                              hipStream_t stream) {
  const float* x        = (const float*)d_in[0];  // [16,512,128,128]
  const float* w        = (const float*)d_in[1];  // [16,512]
  const float* affine_W = (const float*)d_in[2];  // [1536,512]
  const float* affine_b = (const float*)d_in[3];  // [1536]
  const float* conv_w   = (const float*)d_in[4];  // [3,512]
  const float* conv_b   = (const float*)d_in[5];  // [3]
  float* out = (float*)d_out;                     // [16,3,128,128]

  float4* eff4 = (float4*)d_ws;                   // [0, 128 KB)
  float4* part = (float4*)d_ws + PART_OFF_;       // [2 MB, 2 MB + 50.3 MB)

  style_kernel<<<B_ * CIN_, 64, 0, stream>>>(w, affine_W, affine_b, conv_w, eff4);
  conv_partial_kernel<<<B_ * NTILE_ * NGRP_, 256, 0, stream>>>(x, eff4, part);
  reduce_kernel<<<B_ * COUT_ * NTILE_, 256, 0, stream>>>(part, conv_b, (float4*)out);
}

// Round 3
// 654.964 us; speedup vs baseline: 1.0672x; 1.0672x over previous
//
#include <hip/hip_runtime.h>

#define B_      16
#define CIN_    512
#define COUT_   3
#define WDIM_   512
#define HW_     16384            // 128*128
#define FC_GAIN     0.044194173824159216f   // 1/sqrt(512)
#define WEIGHT_GAIN 0.044194173824159216f   // 1/sqrt(512*1)
#define CLAMP_  256.0f

typedef float v4f __attribute__((ext_vector_type(4)));

// Kernel 1: one wave per (b, c). Unchanged from round 0 (~8 us, L2-resident).
__global__ __launch_bounds__(64) void style_kernel(
    const float* __restrict__ w,
    const float* __restrict__ affine_W,
    const float* __restrict__ affine_b,
    const float* __restrict__ conv_w,
    float4* __restrict__ eff4) {
  const int bc   = blockIdx.x;        // 0 .. B*CIN-1
  const int b    = bc >> 9;           // / 512
  const int c    = bc & 511;
  const int lane = threadIdx.x;       // 0..63

  const float* wb = w + b * WDIM_;
  const float* r1 = affine_W + (size_t)c * WDIM_;
  const float* r2 = affine_W + (size_t)(c + CIN_) * WDIM_;
  const float* r3 = affine_W + (size_t)(c + 2 * CIN_) * WDIM_;

  float p1 = 0.f, p2 = 0.f, p3 = 0.f;
#pragma unroll
  for (int j = 0; j < WDIM_ / 64; ++j) {
    const int k = j * 64 + lane;      // coalesced across the wave
    const float wk = wb[k];
    p1 = fmaf(wk, r1[k], p1);
    p2 = fmaf(wk, r2[k], p2);
    p3 = fmaf(wk, r3[k], p3);
  }
#pragma unroll
  for (int off = 32; off > 0; off >>= 1) {
    p1 += __shfl_down(p1, off);
    p2 += __shfl_down(p2, off);
    p3 += __shfl_down(p3, off);
  }
  if (lane == 0) {
    const float s1 = p1 * FC_GAIN + affine_b[c];
    const float s2 = p2 * FC_GAIN + affine_b[c + CIN_];
    const float s3 = p3 * FC_GAIN + affine_b[c + 2 * CIN_];
    const float style = (s1 * s2 + s3) * WEIGHT_GAIN;
    float4 e;
    e.x = conv_w[0 * CIN_ + c] * style;
    e.y = conv_w[1 * CIN_ + c] * style;
    e.z = conv_w[2 * CIN_ + c] * style;
    e.w = 0.f;
    eff4[bc] = e;
  }
}

// Kernel 2: byte-identical structure to round 0 (the 669 us baseline) EXCEPT
// all x loads are nontemporal (`nt` flag: no L2/L3 allocation) and out stores
// are nontemporal. Theory under test: the 2 GiB ws-poison fill leaves L2/L3
// fully dirty; every x-line allocation victimizes a dirty line, and the
// victim/writeback pipeline (not DRAM) is the ~1.7 TB/s wall. x has zero
// reuse, so allocation bypass is semantically free.
__global__ __launch_bounds__(256) void conv_kernel(
    const float* __restrict__ x,
    const float4* __restrict__ eff4,
    const float* __restrict__ conv_b,
    float* __restrict__ out) {
  __shared__ float4 s_eff[CIN_];

  const int b    = blockIdx.x >> 4;   // / 16
  const int tile = blockIdx.x & 15;
  const int tid  = threadIdx.x;

  // stage this batch's effective weights into LDS (8 KB)
  s_eff[tid]       = eff4[b * CIN_ + tid];
  s_eff[tid + 256] = eff4[b * CIN_ + tid + 256];
  __syncthreads();

  // x as v4f: (b*CIN + c)*4096 + tile*256 + tid
  const v4f* xb = (const v4f*)x + ((size_t)b * CIN_) * (HW_ / 4)
                  + (size_t)tile * 256 + tid;

  float a0x = 0.f, a0y = 0.f, a0z = 0.f, a0w = 0.f;
  float a1x = 0.f, a1y = 0.f, a1z = 0.f, a1w = 0.f;
  float a2x = 0.f, a2y = 0.f, a2z = 0.f, a2w = 0.f;

#pragma unroll 8
  for (int c = 0; c < CIN_; ++c) {
    const v4f xv   = __builtin_nontemporal_load(&xb[(size_t)c * (HW_ / 4)]);
    const float4 e = s_eff[c];
    a0x = fmaf(xv.x, e.x, a0x); a0y = fmaf(xv.y, e.x, a0y);
    a0z = fmaf(xv.z, e.x, a0z); a0w = fmaf(xv.w, e.x, a0w);
    a1x = fmaf(xv.x, e.y, a1x); a1y = fmaf(xv.y, e.y, a1y);
    a1z = fmaf(xv.z, e.y, a1z); a1w = fmaf(xv.w, e.y, a1w);
    a2x = fmaf(xv.x, e.z, a2x); a2y = fmaf(xv.y, e.z, a2y);
    a2z = fmaf(xv.z, e.z, a2z); a2w = fmaf(xv.w, e.z, a2w);
  }

  const float b0 = conv_b[0], b1 = conv_b[1], b2 = conv_b[2];
#define CLMP(v, bb) fminf(fmaxf((v) + (bb), -CLAMP_), CLAMP_)
  v4f o0 = { CLMP(a0x, b0), CLMP(a0y, b0), CLMP(a0z, b0), CLMP(a0w, b0) };
  v4f o1 = { CLMP(a1x, b1), CLMP(a1y, b1), CLMP(a1z, b1), CLMP(a1w, b1) };
  v4f o2 = { CLMP(a2x, b2), CLMP(a2y, b2), CLMP(a2z, b2), CLMP(a2w, b2) };
#undef CLMP

  v4f* op = (v4f*)out + ((size_t)b * COUT_) * (HW_ / 4)
            + (size_t)tile * 256 + tid;
  __builtin_nontemporal_store(o0, &op[0]);
  __builtin_nontemporal_store(o1, &op[1 * (HW_ / 4)]);
  __builtin_nontemporal_store(o2, &op[2 * (HW_ / 4)]);
}

extern "C" void kernel_launch(void* const* d_in, const int* in_sizes, int n_in,
                              void* d_out, int out_size, void* d_ws, size_t ws_size,
                              hipStream_t stream) {
  const float* x        = (const float*)d_in[0];  // [16,512,128,128]
  const float* w        = (const float*)d_in[1];  // [16,512]
  const float* affine_W = (const float*)d_in[2];  // [1536,512]
  const float* affine_b = (const float*)d_in[3];  // [1536]
  const float* conv_w   = (const float*)d_in[4];  // [3,512]
  const float* conv_b   = (const float*)d_in[5];  // [3]
  float* out = (float*)d_out;                     // [16,3,128,128]

  float4* eff4 = (float4*)d_ws;                   // 16*512 float4 = 128 KB

  style_kernel<<<B_ * CIN_, 64, 0, stream>>>(w, affine_W, affine_b, conv_w, eff4);
  conv_kernel<<<B_ * 16, 256, 0, stream>>>(x, eff4, conv_b, out);
}